// Round 1
// baseline (13700.768 us; speedup 1.0000x reference)
//
#include <hip/hip_runtime.h>
#include <cstdint>
#include <cstddef>

// ---------------------------------------------------------------------------
// E2E AttDot + 2-layer LSTM decoder + CE loss, bf16 MFMA implementation.
// B=32, T=400, E=D=1024, V=5000, L=100 (101 steps). Loss = mean(CE)*100.
// ---------------------------------------------------------------------------

using short8  = __attribute__((ext_vector_type(8))) short;
using floatx4 = __attribute__((ext_vector_type(4))) float;

#define DEV __device__ __forceinline__

DEV float bf2f(unsigned int h) { union { unsigned int u; float f; } v; v.u = h << 16; return v.f; }
DEV unsigned short f2bf(float f) {
    union { float f; unsigned int u; } v; v.f = f;
    return (unsigned short)((v.u + 0x7fffu + ((v.u >> 16) & 1u)) >> 16);
}
DEV float sigm(float x) { return 1.0f / (1.0f + __expf(-x)); }
DEV void  st_agent(float* p, float v) { __hip_atomic_store(p, v, __ATOMIC_RELAXED, __HIP_MEMORY_SCOPE_AGENT); }
DEV float ld_agent(const float* p) { return __hip_atomic_load(p, __ATOMIC_RELAXED, __HIP_MEMORY_SCOPE_AGENT); }

// ---------------------------------------------------------------- utilities
__global__ __launch_bounds__(256) void k_zero(unsigned int* p, int n) {
    int i = blockIdx.x * 256 + threadIdx.x;
    if (i < n) p[i] = 0u;
}

__global__ __launch_bounds__(256) void k_conv4(const float* __restrict__ in,
                                               unsigned short* __restrict__ out, int n4) {
    int i = blockIdx.x * 256 + threadIdx.x;
    if (i >= n4) return;
    float4 v = ((const float4*)in)[i];
    unsigned int w0 = (unsigned int)f2bf(v.x) | ((unsigned int)f2bf(v.y) << 16);
    unsigned int w1 = (unsigned int)f2bf(v.z) | ((unsigned int)f2bf(v.w) << 16);
    ((uint2*)(void*)out)[i] = make_uint2(w0, w1);
}

// dst[n][0:Ka] = A[n], dst[n][Ka:Ka+Kb] = Bsrc[n]   (bf16)
__global__ __launch_bounds__(256) void k_cat2(const float* __restrict__ A, const float* __restrict__ Bsrc,
                                              unsigned short* __restrict__ dst, int N, int Ka, int Kb) {
    int idx = blockIdx.x * 256 + threadIdx.x;
    int K = Ka + Kb;
    if (idx >= N * K) return;
    int n = idx / K, k = idx - n * K;
    float v = (k < Ka) ? A[(size_t)n * Ka + k] : Bsrc[(size_t)n * Kb + (k - Ka)];
    dst[idx] = f2bf(v);
}

// Wout [5000][2048] f32 -> [5120][2048] bf16 zero-padded rows
__global__ __launch_bounds__(256) void k_woutpad(const float* __restrict__ W, unsigned short* __restrict__ dst) {
    int idx = blockIdx.x * 256 + threadIdx.x;
    if (idx >= 5120 * 2048) return;
    int n = idx >> 11, k = idx & 2047;
    dst[idx] = (n < 5000) ? f2bf(W[(size_t)n * 2048 + k]) : (unsigned short)0;
}

__global__ __launch_bounds__(256) void k_bsum(const float* a0, const float* b0, const float* a1, const float* b1,
                                              float* s0, float* s1) {
    int i = blockIdx.x * 256 + threadIdx.x;
    if (i < 4096) s0[i] = a0[i] + b0[i];
    else if (i < 8192) s1[i - 4096] = a1[i - 4096] + b1[i - 4096];
}

// eys[l][b][d] = bf16(embed[ys_in[b][l]][d]); ys_in[b][0]=SOS, else ys_pad[b][l-1]
__global__ __launch_bounds__(256) void k_eys(const float* __restrict__ embed, const int* __restrict__ ys_pad,
                                             unsigned short* __restrict__ eys) {
    int idx = blockIdx.x * 256 + threadIdx.x;
    if (idx >= 3232 * 1024) return;
    int rb = idx >> 10, d = idx & 1023;
    int l = rb >> 5, b = rb & 31;
    int tok = (l == 0) ? 4999 : ys_pad[b * 100 + (l - 1)];
    eys[idx] = f2bf(embed[(size_t)tok * 1024 + d]);
}

// --------------------------------------------------- big 128x128 MFMA GEMM
// C[m][n] = sum_k A[m][k]*B[n][k];  mode0: out_bf16 = bf16(tanh(C + bias[n]))
//                                   mode1: out_f32  = C
// M = gridDim.y*128, N = gridDim.x*128, K % 32 == 0. No bounds (all padded).
__global__ __launch_bounds__(256) void k_gemm128(
    const unsigned short* __restrict__ A, const unsigned short* __restrict__ B,
    int K, int N, const float* __restrict__ bias,
    unsigned short* __restrict__ obf, float* __restrict__ of32, int mode) {
    __shared__ uint4 Ab[512];  // 8 fragment-tiles (16 rows x 32 k), lane-ordered
    __shared__ uint4 Bb[512];
    const int tid = threadIdx.x;
    const int lane = tid & 63, wave = tid >> 6;
    const int r = lane & 15, q = lane >> 4;
    const int wm = wave >> 1, wn = wave & 1;
    const size_t am0 = (size_t)blockIdx.y * 128;
    const size_t bn0 = (size_t)blockIdx.x * 128;
    floatx4 zf = {0.f, 0.f, 0.f, 0.f};
    floatx4 acc[4][4];
#pragma unroll
    for (int i = 0; i < 4; i++)
#pragma unroll
        for (int j = 0; j < 4; j++) acc[i][j] = zf;

    for (int k0 = 0; k0 < K; k0 += 32) {
        __syncthreads();
#pragma unroll
        for (int i = 0; i < 2; ++i) {
            int idx = i * 256 + tid;           // cell = (row rr, k-quarter qq)
            int qq = idx & 3, rr = idx >> 2;
            int slot = (rr >> 4) * 64 + ((qq << 4) | (rr & 15));
            Ab[slot] = *(const uint4*)(const void*)(A + (am0 + rr) * K + k0 + qq * 8);
            Bb[slot] = *(const uint4*)(const void*)(B + (bn0 + rr) * K + k0 + qq * 8);
        }
        __syncthreads();
        short8 af[4], bf[4];
#pragma unroll
        for (int t = 0; t < 4; t++) af[t] = *(const short8*)(const void*)&Ab[(wm * 4 + t) * 64 + lane];
#pragma unroll
        for (int t = 0; t < 4; t++) bf[t] = *(const short8*)(const void*)&Bb[(wn * 4 + t) * 64 + lane];
#pragma unroll
        for (int tm = 0; tm < 4; tm++)
#pragma unroll
            for (int tn = 0; tn < 4; tn++)
                acc[tm][tn] = __builtin_amdgcn_mfma_f32_16x16x32_bf16(af[tm], bf[tn], acc[tm][tn], 0, 0, 0);
    }
#pragma unroll
    for (int tm = 0; tm < 4; tm++) {
#pragma unroll
        for (int tn = 0; tn < 4; tn++) {
            int col = (int)bn0 + wn * 64 + tn * 16 + r;
#pragma unroll
            for (int reg = 0; reg < 4; ++reg) {
                size_t row = am0 + wm * 64 + tm * 16 + q * 4 + reg;
                float v = acc[tm][tn][reg];
                if (mode == 0) {
                    v = tanhf(v + bias[col]);
                    obf[row * (size_t)N + col] = f2bf(v);
                } else {
                    of32[row * (size_t)N + col] = v;
                }
            }
        }
    }
}

// ------------------------------------------------------------ dq (32x1024)
// dq[b][d] = tanh( sum_k z0[b][k]*Wdec[d][k] + bdec[d] ), one block = 16 d's
DEV void dq_role(int dcq, const unsigned short* __restrict__ Wdec,
                 const unsigned short* __restrict__ z0, const float* __restrict__ bdec,
                 unsigned short* __restrict__ dq) {
    const int tid = threadIdx.x, lane = tid & 63, wave = tid >> 6;
    if (wave >= 2) return;
    const int r = lane & 15, q = lane >> 4, mt = wave;
    floatx4 acc = {0.f, 0.f, 0.f, 0.f};
    const unsigned short* Brow = Wdec + (size_t)(dcq * 16 + r) * 1024;
    const unsigned short* Arow = z0 + (size_t)(mt * 16 + r) * 1024;
    for (int k0 = 0; k0 < 1024; k0 += 32) {
        short8 bfr = *(const short8*)(const void*)(Brow + k0 + q * 8);
        short8 afr = *(const short8*)(const void*)(Arow + k0 + q * 8);
        acc = __builtin_amdgcn_mfma_f32_16x16x32_bf16(afr, bfr, acc, 0, 0, 0);
    }
    const int n = dcq * 16 + r;
#pragma unroll
    for (int reg = 0; reg < 4; ++reg) {
        int m = mt * 16 + q * 4 + reg;
        dq[m * 1024 + n] = f2bf(tanhf(acc[reg] + bdec[n]));
    }
}

__global__ __launch_bounds__(256) void k_dq(const unsigned short* __restrict__ Wdec,
                                            const unsigned short* __restrict__ z0,
                                            const float* __restrict__ bdec,
                                            unsigned short* __restrict__ dq) {
    dq_role(blockIdx.x, Wdec, z0, bdec, dq);
}

// ------------------------------------------------------- attention per step
// grid 256 = 32 b x 8 chunks(50 t). Computes e, chunk-local softmax partials,
// partial att_c; last block per b merges -> att_bf16[b][:] and z_all att half.
__global__ __launch_bounds__(256) void k_att(
    const unsigned short* __restrict__ pre, const unsigned short* __restrict__ hs,
    const unsigned short* __restrict__ dq, const int* __restrict__ hlens,
    float* __restrict__ part,               // [32][8][1024]
    float* __restrict__ lmax_g, float* __restrict__ lsum_g,  // [32][8]
    unsigned short* __restrict__ att,       // [32][1024]
    unsigned short* __restrict__ z_all,     // [3328][2048]
    int* __restrict__ cnt, int step) {
    const int b = blockIdx.x >> 3, ch = blockIdx.x & 7;
    const int tid = threadIdx.x, lane = tid & 63, wave = tid >> 6;
    const int hlen = hlens[b];
    __shared__ float e_s[50];
    __shared__ float p_s[50];
    __shared__ int lastflag;

    float dqf[16];
    {
        const uint4* dp = (const uint4*)(const void*)(dq + b * 1024 + lane * 16);
        uint4 w0 = dp[0], w1 = dp[1];
        dqf[0] = bf2f(w0.x & 0xffffu); dqf[1] = bf2f(w0.x >> 16);
        dqf[2] = bf2f(w0.y & 0xffffu); dqf[3] = bf2f(w0.y >> 16);
        dqf[4] = bf2f(w0.z & 0xffffu); dqf[5] = bf2f(w0.z >> 16);
        dqf[6] = bf2f(w0.w & 0xffffu); dqf[7] = bf2f(w0.w >> 16);
        dqf[8]  = bf2f(w1.x & 0xffffu); dqf[9]  = bf2f(w1.x >> 16);
        dqf[10] = bf2f(w1.y & 0xffffu); dqf[11] = bf2f(w1.y >> 16);
        dqf[12] = bf2f(w1.z & 0xffffu); dqf[13] = bf2f(w1.z >> 16);
        dqf[14] = bf2f(w1.w & 0xffffu); dqf[15] = bf2f(w1.w >> 16);
    }
    for (int tl = wave; tl < 50; tl += 4) {
        int t = ch * 50 + tl;
        const uint4* pp = (const uint4*)(const void*)(pre + ((size_t)(b * 400 + t)) * 1024 + lane * 16);
        uint4 v0 = pp[0], v1 = pp[1];
        float s = 0.f;
        s += bf2f(v0.x & 0xffffu) * dqf[0] + bf2f(v0.x >> 16) * dqf[1];
        s += bf2f(v0.y & 0xffffu) * dqf[2] + bf2f(v0.y >> 16) * dqf[3];
        s += bf2f(v0.z & 0xffffu) * dqf[4] + bf2f(v0.z >> 16) * dqf[5];
        s += bf2f(v0.w & 0xffffu) * dqf[6] + bf2f(v0.w >> 16) * dqf[7];
        s += bf2f(v1.x & 0xffffu) * dqf[8]  + bf2f(v1.x >> 16) * dqf[9];
        s += bf2f(v1.y & 0xffffu) * dqf[10] + bf2f(v1.y >> 16) * dqf[11];
        s += bf2f(v1.z & 0xffffu) * dqf[12] + bf2f(v1.z >> 16) * dqf[13];
        s += bf2f(v1.w & 0xffffu) * dqf[14] + bf2f(v1.w >> 16) * dqf[15];
#pragma unroll
        for (int off = 32; off; off >>= 1) s += __shfl_xor(s, off, 64);
        if (lane == 0) e_s[tl] = (t < hlen) ? 2.0f * s : -1e30f;
    }
    __syncthreads();
    float lmax = -1e30f;
    for (int i = 0; i < 50; ++i) lmax = fmaxf(lmax, e_s[i]);
    if (tid < 50) p_s[tid] = (e_s[tid] > -5e29f) ? __expf(e_s[tid] - lmax) : 0.f;
    __syncthreads();
    if (tid == 0) {
        float ssum = 0.f;
        for (int i = 0; i < 50; ++i) ssum += p_s[i];
        st_agent(&lmax_g[b * 8 + ch], lmax);
        st_agent(&lsum_g[b * 8 + ch], ssum);
    }
    // partial att_c: this thread owns cols [c, c+4)
    const int c = tid * 4;
    float a0 = 0.f, a1 = 0.f, a2 = 0.f, a3 = 0.f;
    for (int tl = 0; tl < 50; ++tl) {
        float p = p_s[tl];
        if (p > 0.f) {
            uint2 h = *(const uint2*)(const void*)(hs + ((size_t)(b * 400 + ch * 50 + tl)) * 1024 + c);
            a0 += p * bf2f(h.x & 0xffffu); a1 += p * bf2f(h.x >> 16);
            a2 += p * bf2f(h.y & 0xffffu); a3 += p * bf2f(h.y >> 16);
        }
    }
    float* pb = part + ((size_t)(b * 8 + ch)) * 1024 + c;
    st_agent(pb + 0, a0); st_agent(pb + 1, a1); st_agent(pb + 2, a2); st_agent(pb + 3, a3);
    __threadfence();
    __syncthreads();
    if (tid == 0) lastflag = (atomicAdd(cnt + b, 1) == 8 * step + 7);
    __syncthreads();
    if (!lastflag) return;
    __threadfence();
    // merge 8 chunks
    float lm[8], ls[8];
#pragma unroll
    for (int i = 0; i < 8; ++i) { lm[i] = ld_agent(&lmax_g[b * 8 + i]); ls[i] = ld_agent(&lsum_g[b * 8 + i]); }
    float gm = -1e30f;
#pragma unroll
    for (int i = 0; i < 8; ++i) gm = fmaxf(gm, lm[i]);
    float Z = 0.f;
#pragma unroll
    for (int i = 0; i < 8; ++i) Z += ls[i] * __expf(lm[i] - gm);
    const float inv = 1.0f / Z;
    float coef[8];
#pragma unroll
    for (int i = 0; i < 8; ++i) coef[i] = __expf(lm[i] - gm) * inv;
    float o[4] = {0.f, 0.f, 0.f, 0.f};
#pragma unroll
    for (int i = 0; i < 8; ++i) {
        const float* q = part + ((size_t)(b * 8 + i)) * 1024 + c;
        o[0] += coef[i] * ld_agent(q + 0);
        o[1] += coef[i] * ld_agent(q + 1);
        o[2] += coef[i] * ld_agent(q + 2);
        o[3] += coef[i] * ld_agent(q + 3);
    }
#pragma unroll
    for (int j = 0; j < 4; ++j) {
        unsigned short v = f2bf(o[j]);
        att[b * 1024 + c + j] = v;
        z_all[((size_t)(step * 32 + b)) * 2048 + 1024 + c + j] = v;
    }
}

// ------------------------------------------------------------ LSTM cell 0
// gates[b][n] = sum_k x[b][k]*Wcat0[n][k], x=[ey|att|z0old] (K=3072), split-K x4.
// grid 256 = 64 d-chunks x 4 k-chunks; last k-chunk block per d-chunk combines
// + applies LSTM pointwise -> z0new (bf16 [32][1024]), c0 (f32 [1024][32]).
__global__ __launch_bounds__(256) void k_cell0(
    const unsigned short* __restrict__ Wcat0, const unsigned short* __restrict__ eys,
    const unsigned short* __restrict__ att, const unsigned short* __restrict__ z0old,
    unsigned short* __restrict__ z0new, float* __restrict__ c0,
    float* __restrict__ gp, const float* __restrict__ bsum0,
    int* __restrict__ cnt, int step) {
    const int tid = threadIdx.x, lane = tid & 63, g = tid >> 6;
    const int r = lane & 15, q = lane >> 4;
    const int dc = blockIdx.x >> 2, kc = blockIdx.x & 3;
    const unsigned short* eys_l = eys + (size_t)step * 32 * 1024;
    const unsigned short* Brow = Wcat0 + (size_t)(g * 1024 + dc * 16 + r) * 3072;
    floatx4 zf = {0.f, 0.f, 0.f, 0.f};
    floatx4 acc0 = zf, acc1 = zf;
    for (int kk = 0; kk < 768; kk += 32) {
        const int k0 = kc * 768 + kk;
        const unsigned short* asrc; int col;
        if (k0 < 1024)      { asrc = eys_l; col = k0; }
        else if (k0 < 2048) { asrc = att;   col = k0 - 1024; }
        else                { asrc = z0old; col = k0 - 2048; }
        short8 bfr = *(const short8*)(const void*)(Brow + k0 + q * 8);
        short8 a0  = *(const short8*)(const void*)(asrc + (size_t)r * 1024 + col + q * 8);
        short8 a1  = *(const short8*)(const void*)(asrc + (size_t)(r + 16) * 1024 + col + q * 8);
        acc0 = __builtin_amdgcn_mfma_f32_16x16x32_bf16(a0, bfr, acc0, 0, 0, 0);
        acc1 = __builtin_amdgcn_mfma_f32_16x16x32_bf16(a1, bfr, acc1, 0, 0, 0);
    }
    const int n = g * 1024 + dc * 16 + r;
    float* gb = gp + ((size_t)kc * 4096 + n) * 32;
#pragma unroll
    for (int reg = 0; reg < 4; ++reg) {
        st_agent(gb + q * 4 + reg, acc0[reg]);
        st_agent(gb + 16 + q * 4 + reg, acc1[reg]);
    }
    __threadfence();
    __syncthreads();
    __shared__ int lastflag;
    if (tid == 0) lastflag = (atomicAdd(cnt + dc, 1) == 4 * step + 3);
    __syncthreads();
    if (!lastflag) return;
    __threadfence();
    for (int idx = tid; idx < 512; idx += 256) {
        const int bb = idx & 31, dl = idx >> 5;
        const int d = dc * 16 + dl;
        float gg[4];
#pragma unroll
        for (int gate = 0; gate < 4; ++gate) {
            float s = bsum0[gate * 1024 + d];
#pragma unroll
            for (int kcc = 0; kcc < 4; ++kcc)
                s += ld_agent(gp + ((size_t)kcc * 4096 + gate * 1024 + d) * 32 + bb);
            gg[gate] = s;
        }
        const float cn = sigm(gg[1]) * c0[d * 32 + bb] + sigm(gg[0]) * tanhf(gg[2]);
        c0[d * 32 + bb] = cn;
        z0new[bb * 1024 + d] = f2bf(sigm(gg[3]) * tanhf(cn));
    }
}

// --------------------------------------------- LSTM cell 1 + next-step dq
__global__ __launch_bounds__(256) void k_cell1dq(
    const unsigned short* __restrict__ Wcat1, const unsigned short* __restrict__ z0new,
    const unsigned short* __restrict__ z1old, unsigned short* __restrict__ z1new,
    float* __restrict__ c1, float* __restrict__ gp, const float* __restrict__ bsum1,
    int* __restrict__ cnt, const unsigned short* __restrict__ Wdec,
    const float* __restrict__ bdec, unsigned short* __restrict__ dq,
    unsigned short* __restrict__ z_all, int step) {
    const int bi = blockIdx.x;
    if (bi >= 256) { dq_role(bi - 256, Wdec, z0new, bdec, dq); return; }
    const int tid = threadIdx.x, lane = tid & 63, g = tid >> 6;
    const int r = lane & 15, q = lane >> 4;
    const int dc = bi >> 2, kc = bi & 3;
    const unsigned short* Brow = Wcat1 + (size_t)(g * 1024 + dc * 16 + r) * 2048;
    floatx4 zf = {0.f, 0.f, 0.f, 0.f};
    floatx4 acc0 = zf, acc1 = zf;
    for (int kk = 0; kk < 512; kk += 32) {
        const int k0 = kc * 512 + kk;
        const unsigned short* asrc = (k0 < 1024) ? z0new : z1old;
        const int col = k0 & 1023;
        short8 bfr = *(const short8*)(const void*)(Brow + k0 + q * 8);
        short8 a0  = *(const short8*)(const void*)(asrc + (size_t)r * 1024 + col + q * 8);
        short8 a1  = *(const short8*)(const void*)(asrc + (size_t)(r + 16) * 1024 + col + q * 8);
        acc0 = __builtin_amdgcn_mfma_f32_16x16x32_bf16(a0, bfr, acc0, 0, 0, 0);
        acc1 = __builtin_amdgcn_mfma_f32_16x16x32_bf16(a1, bfr, acc1, 0, 0, 0);
    }
    const int n = g * 1024 + dc * 16 + r;
    float* gb = gp + ((size_t)kc * 4096 + n) * 32;
#pragma unroll
    for (int reg = 0; reg < 4; ++reg) {
        st_agent(gb + q * 4 + reg, acc0[reg]);
        st_agent(gb + 16 + q * 4 + reg, acc1[reg]);
    }
    __threadfence();
    __syncthreads();
    __shared__ int lastflag;
    if (tid == 0) lastflag = (atomicAdd(cnt + dc, 1) == 4 * step + 3);
    __syncthreads();
    if (!lastflag) return;
    __threadfence();
    for (int idx = tid; idx < 512; idx += 256) {
        const int bb = idx & 31, dl = idx >> 5;
        const int d = dc * 16 + dl;
        float gg[4];
#pragma unroll
        for (int gate = 0; gate < 4; ++gate) {
            float s = bsum1[gate * 1024 + d];
#pragma unroll
            for (int kcc = 0; kcc < 4; ++kcc)
                s += ld_agent(gp + ((size_t)kcc * 4096 + gate * 1024 + d) * 32 + bb);
            gg[gate] = s;
        }
        const float cn = sigm(gg[1]) * c1[d * 32 + bb] + sigm(gg[0]) * tanhf(gg[2]);
        c1[d * 32 + bb] = cn;
        const unsigned short hb = f2bf(sigm(gg[3]) * tanhf(cn));
        z1new[bb * 1024 + d] = hb;
        z_all[((size_t)(step * 32 + bb)) * 2048 + d] = hb;
    }
}

// ----------------------------------------------------------- CE reduction
// one block per (l,b) row of y [3232][5120]; logits = y + bout, cols < 5000
__global__ __launch_bounds__(256) void k_ce(const float* __restrict__ y, const float* __restrict__ bout,
                                            const int* __restrict__ ys_pad, float* __restrict__ out) {
    const int rrow = blockIdx.x;
    const int l = rrow >> 5, b = rrow & 31;
    const float* yp = y + (size_t)rrow * 5120;
    const int tid = threadIdx.x;
    __shared__ float red[256];
    float m = -1e30f;
    for (int c = tid; c < 5000; c += 256) m = fmaxf(m, yp[c] + bout[c]);
    red[tid] = m; __syncthreads();
    for (int s = 128; s; s >>= 1) { if (tid < s) red[tid] = fmaxf(red[tid], red[tid + s]); __syncthreads(); }
    const float gmax = red[0]; __syncthreads();
    float ss = 0.f;
    for (int c = tid; c < 5000; c += 256) ss += __expf(yp[c] + bout[c] - gmax);
    red[tid] = ss; __syncthreads();
    for (int s = 128; s; s >>= 1) { if (tid < s) red[tid] += red[tid + s]; __syncthreads(); }
    if (tid == 0) {
        const int tgt = (l < 100) ? ys_pad[b * 100 + l] : 4999;
        const float lt = yp[tgt] + bout[tgt];
        const float ce = logf(red[0]) + gmax - lt;
        atomicAdd(out, ce * (100.0f / 3232.0f));
    }
}

// ---------------------------------------------------------------------------
extern "C" void kernel_launch(void* const* d_in, const int* in_sizes, int n_in,
                              void* d_out, int out_size, void* d_ws, size_t ws_size,
                              hipStream_t stream) {
    const float* hs_pad = (const float*)d_in[0];
    const float* embed  = (const float*)d_in[1];
    const float* Wenc   = (const float*)d_in[2];
    const float* benc   = (const float*)d_in[3];
    const float* Wdec   = (const float*)d_in[4];
    const float* bdec   = (const float*)d_in[5];
    const float* W_ih0  = (const float*)d_in[6];
    const float* W_hh0  = (const float*)d_in[7];
    const float* b_ih0  = (const float*)d_in[8];
    const float* b_hh0  = (const float*)d_in[9];
    const float* W_ih1  = (const float*)d_in[10];
    const float* W_hh1  = (const float*)d_in[11];
    const float* b_ih1  = (const float*)d_in[12];
    const float* b_hh1  = (const float*)d_in[13];
    const float* Wout   = (const float*)d_in[14];
    const float* bout   = (const float*)d_in[15];
    const int*   hlens  = (const int*)d_in[16];
    const int*   ys_pad = (const int*)d_in[17];
    float* out = (float*)d_out;
    uint8_t* ws = (uint8_t*)d_ws;

    // workspace layout (bytes); y (f32 [3328][5120], 68.2MB) aliases
    // [HS|PRE|WC0] which are dead by the final GEMM.
    constexpr size_t OFF_HS   = 0;                              // 26,214,400
    constexpr size_t OFF_PRE  = OFF_HS   + 26214400;            // 26,214,400
    constexpr size_t OFF_WC0  = OFF_PRE  + 26214400;            // 25,165,824
    constexpr size_t OFF_WC1  = OFF_WC0  + 25165824;            // 16,777,216
    constexpr size_t OFF_WOUT = OFF_WC1  + 16777216;            // 20,971,520
    constexpr size_t OFF_WENC = OFF_WOUT + 20971520;            // 2,097,152
    constexpr size_t OFF_WDEC = OFF_WENC + 2097152;             // 2,097,152
    constexpr size_t OFF_EYS  = OFF_WDEC + 2097152;             // 6,619,136
    constexpr size_t OFF_ZALL = OFF_EYS  + 6619136;             // 13,631,488
    constexpr size_t OFF_GP   = OFF_ZALL + 13631488;            // 2,097,152
    constexpr size_t OFF_PART = OFF_GP   + 2097152;             // 1,048,576
    constexpr size_t OFF_LMAX = OFF_PART + 1048576;             // 1,024
    constexpr size_t OFF_LSUM = OFF_LMAX + 1024;                // 1,024
    constexpr size_t OFF_ATT  = OFF_LSUM + 1024;                // 65,536
    constexpr size_t OFF_DQ   = OFF_ATT  + 65536;               // 65,536
    constexpr size_t OFF_Z0A  = OFF_DQ   + 65536;               // 65,536
    constexpr size_t OFF_Z0B  = OFF_Z0A  + 65536;               // 65,536
    constexpr size_t OFF_Z1A  = OFF_Z0B  + 65536;               // 65,536
    constexpr size_t OFF_Z1B  = OFF_Z1A  + 65536;               // 65,536
    constexpr size_t OFF_C0   = OFF_Z1B  + 65536;               // 131,072
    constexpr size_t OFF_C1   = OFF_C0   + 131072;              // 131,072
    constexpr size_t OFF_BS0  = OFF_C1   + 131072;              // 16,384
    constexpr size_t OFF_BS1  = OFF_BS0  + 16384;               // 16,384
    constexpr size_t OFF_CNT  = OFF_BS1  + 16384;               // 640
    constexpr size_t OFF_Y    = 0;

    unsigned short* HS   = (unsigned short*)(ws + OFF_HS);
    unsigned short* PRE  = (unsigned short*)(ws + OFF_PRE);
    unsigned short* WC0  = (unsigned short*)(ws + OFF_WC0);
    unsigned short* WC1  = (unsigned short*)(ws + OFF_WC1);
    unsigned short* WOUTP= (unsigned short*)(ws + OFF_WOUT);
    unsigned short* WENC = (unsigned short*)(ws + OFF_WENC);
    unsigned short* WDEC = (unsigned short*)(ws + OFF_WDEC);
    unsigned short* EYS  = (unsigned short*)(ws + OFF_EYS);
    unsigned short* ZALL = (unsigned short*)(ws + OFF_ZALL);
    float* GP    = (float*)(ws + OFF_GP);
    float* PART  = (float*)(ws + OFF_PART);
    float* LMAX  = (float*)(ws + OFF_LMAX);
    float* LSUM  = (float*)(ws + OFF_LSUM);
    unsigned short* ATT = (unsigned short*)(ws + OFF_ATT);
    unsigned short* DQ  = (unsigned short*)(ws + OFF_DQ);
    unsigned short* Z0A = (unsigned short*)(ws + OFF_Z0A);
    unsigned short* Z0B = (unsigned short*)(ws + OFF_Z0B);
    unsigned short* Z1A = (unsigned short*)(ws + OFF_Z1A);
    unsigned short* Z1B = (unsigned short*)(ws + OFF_Z1B);
    float* C0   = (float*)(ws + OFF_C0);
    float* C1   = (float*)(ws + OFF_C1);
    float* BS0  = (float*)(ws + OFF_BS0);
    float* BS1  = (float*)(ws + OFF_BS1);
    int* CNT_ATT = (int*)(ws + OFF_CNT);
    int* CNT0    = CNT_ATT + 32;
    int* CNT1    = CNT_ATT + 96;
    float* Y = (float*)(ws + OFF_Y);

    auto Z = [&](void* p, int n_u32) {
        k_zero<<<dim3((n_u32 + 255) / 256), dim3(256), 0, stream>>>((unsigned int*)p, n_u32);
    };

    // ---- setup (re-done every call: ws/out are re-poisoned by the harness)
    Z(Z0A, 16384); Z(Z1A, 16384);
    Z(C0, 32768);  Z(C1, 32768);
    Z(CNT_ATT, 160);
    Z(d_out, 1);
    Z(ZALL + (size_t)3232 * 2048, 98304);  // pad rows of z_all

    k_conv4<<<dim3(12800), dim3(256), 0, stream>>>(hs_pad, HS, 3276800);
    k_conv4<<<dim3(1024),  dim3(256), 0, stream>>>(Wenc, WENC, 262144);
    k_conv4<<<dim3(1024),  dim3(256), 0, stream>>>(Wdec, WDEC, 262144);
    k_cat2<<<dim3(49152), dim3(256), 0, stream>>>(W_ih0, W_hh0, WC0, 4096, 2048, 1024);
    k_cat2<<<dim3(32768), dim3(256), 0, stream>>>(W_ih1, W_hh1, WC1, 4096, 1024, 1024);
    k_woutpad<<<dim3(40960), dim3(256), 0, stream>>>(Wout, WOUTP);
    k_bsum<<<dim3(32), dim3(256), 0, stream>>>(b_ih0, b_hh0, b_ih1, b_hh1, BS0, BS1);
    k_eys<<<dim3(12928), dim3(256), 0, stream>>>(embed, ys_pad, EYS);

    // pre_enc = tanh(hs @ Wenc^T + benc), [12800][1024] bf16
    k_gemm128<<<dim3(8, 100), dim3(256), 0, stream>>>(HS, WENC, 1024, 1024, benc, PRE, (float*)nullptr, 0);
    // initial dq from z0 = 0
    k_dq<<<dim3(64), dim3(256), 0, stream>>>(WDEC, Z0A, bdec, DQ);

    // ---- the scan: 101 steps, 3 kernels each
    for (int l = 0; l < 101; ++l) {
        unsigned short* z0o = (l & 1) ? Z0B : Z0A;
        unsigned short* z0n = (l & 1) ? Z0A : Z0B;
        unsigned short* z1o = (l & 1) ? Z1B : Z1A;
        unsigned short* z1n = (l & 1) ? Z1A : Z1B;
        k_att<<<dim3(256), dim3(256), 0, stream>>>(PRE, HS, DQ, hlens, PART, LMAX, LSUM, ATT, ZALL, CNT_ATT, l);
        k_cell0<<<dim3(256), dim3(256), 0, stream>>>(WC0, EYS, ATT, z0o, z0n, C0, GP, BS0, CNT0, l);
        k_cell1dq<<<dim3(320), dim3(256), 0, stream>>>(WC1, z0n, z1o, z1n, C1, GP, BS1, CNT1, WDEC, bdec, DQ, ZALL, l);
    }

    // ---- output projection + CE
    k_gemm128<<<dim3(40, 26), dim3(256), 0, stream>>>(ZALL, WOUTP, 2048, 5120, (const float*)nullptr,
                                                      (unsigned short*)nullptr, Y, 1);
    k_ce<<<dim3(3232), dim3(256), 0, stream>>>(Y, bout, ys_pad, out);
}